// Round 4
// baseline (264.439 us; speedup 1.0000x reference)
//
#include <hip/hip_runtime.h>

// OHEM cross-entropy: per-pixel CE over C=19 channels, mean of losses > 0.7.
// logits [8,19,512,1024] f32 (N(0,1) -> no-max logsumexp is safe),
// targets [8,512,1024] i32.
//
// R4: single fused kernel. Per-block partials -> device fence -> arrival
// counter -> last block reduces 4096 partials and writes out[0], overlapping
// the grid tail. One 4B memsetAsync zeroes the counter each launch
// (ws is poisoned 0xAA once and never re-poisoned -> must self-init).
// Main compute path identical to R2/R3 (95% of copy-bench BW).

typedef float f32x4 __attribute__((ext_vector_type(4)));
typedef int   i32x4 __attribute__((ext_vector_type(4)));

constexpr int       C_      = 19;
constexpr int       HW_     = 512 * 1024;          // 2^19
constexpr long long CHW_    = (long long)C_ * HW_;
constexpr int       NPIX_   = 8 * HW_;             // 4194304
constexpr int       NVEC_   = NPIX_ / 4;           // 1048576
constexpr float     THRESH_ = 0.7f;
constexpr int       IGNORE_ = 255;
constexpr int       BLOCK_  = 256;
constexpr int       GRID_   = NVEC_ / BLOCK_;      // 4096 blocks

__global__ __launch_bounds__(BLOCK_, 8) void ohem_ce_fused(
    const float* __restrict__ logits,
    const int*   __restrict__ targets,
    float*        __restrict__ blk_sum,
    unsigned int* __restrict__ blk_cnt,
    unsigned int* __restrict__ arrive,
    float*        __restrict__ out)
{
    const int tid = blockIdx.x * BLOCK_ + threadIdx.x;   // grid exactly covers NVEC_
    const int p0  = tid << 2;
    const int b   = p0 >> 19;                            // / HW_
    const int rem = p0 & (HW_ - 1);
    const float* base = logits + (long long)b * CHW_ + rem;

    const i32x4 tg = __builtin_nontemporal_load(
        reinterpret_cast<const i32x4*>(targets + p0));

    int ct[4];
    #pragma unroll
    for (int j = 0; j < 4; ++j) ct[j] = min(max(tg[j], 0), C_ - 1);

    float s[4]  = {0.f, 0.f, 0.f, 0.f};
    float xt[4] = {0.f, 0.f, 0.f, 0.f};

    #pragma unroll
    for (int c = 0; c < C_; ++c) {
        const f32x4 v = __builtin_nontemporal_load(
            reinterpret_cast<const f32x4*>(base + (long long)c * HW_));
        #pragma unroll
        for (int j = 0; j < 4; ++j) {
            s[j] += __expf(v[j]);
            if (c == ct[j]) xt[j] = v[j];   // select, never runtime-index regs
        }
    }

    float        lsum = 0.0f;
    unsigned int lcnt = 0u;
    #pragma unroll
    for (int j = 0; j < 4; ++j) {
        const float loss = __logf(s[j]) - xt[j];         // logsumexp (no max) - x_t
        if (tg[j] != IGNORE_ && loss > THRESH_) { lsum += loss; lcnt += 1u; }
    }

    // 64-lane wave reduction
    #pragma unroll
    for (int off = 32; off > 0; off >>= 1) {
        lsum += __shfl_down(lsum, off);
        lcnt += __shfl_down(lcnt, off);
    }

    __shared__ float        s_sum[4];
    __shared__ unsigned int s_cnt[4];
    const int lane = threadIdx.x & 63;
    const int wid  = threadIdx.x >> 6;
    if (lane == 0) { s_sum[wid] = lsum; s_cnt[wid] = lcnt; }
    __syncthreads();

    __shared__ unsigned int s_order;
    if (threadIdx.x == 0) {
        blk_sum[blockIdx.x] = s_sum[0] + s_sum[1] + s_sum[2] + s_sum[3];
        blk_cnt[blockIdx.x] = s_cnt[0] + s_cnt[1] + s_cnt[2] + s_cnt[3];
        __threadfence();                                  // release partials (cross-XCD)
        s_order = atomicAdd(arrive, 1u);                  // device-scope by default
    }
    __syncthreads();
    if (s_order != GRID_ - 1) return;

    // ---- last block: reduce all 4096 partials (overlaps other blocks' tails)
    __threadfence();                                      // acquire
    const int t = threadIdx.x;
    double       ds = 0.0;
    unsigned int dc = 0u;
    #pragma unroll
    for (int g = 0; g < 4; ++g) {                         // 256 thr x 4 x f32x4 = 4096
        const int i4 = (g * BLOCK_ + t) << 2;
        const f32x4 s4 = *reinterpret_cast<const f32x4*>(blk_sum + i4);
        const i32x4 c4 = *reinterpret_cast<const i32x4*>(
            reinterpret_cast<const int*>(blk_cnt) + i4);
        ds += (double)s4[0] + (double)s4[1] + (double)s4[2] + (double)s4[3];
        dc += (unsigned int)(c4[0] + c4[1] + c4[2] + c4[3]);
    }
    #pragma unroll
    for (int off = 32; off > 0; off >>= 1) {
        ds += __shfl_down(ds, off);
        dc += __shfl_down(dc, off);
    }
    __shared__ double       sd[4];
    __shared__ unsigned int sc[4];
    if (lane == 0) { sd[wid] = ds; sc[wid] = dc; }
    __syncthreads();
    if (t == 0) {
        const double       tot = sd[0] + sd[1] + sd[2] + sd[3];
        const unsigned int cnt = sc[0] + sc[1] + sc[2] + sc[3];
        out[0] = (float)(tot / (double)(cnt ? cnt : 1u));
    }
}

extern "C" void kernel_launch(void* const* d_in, const int* in_sizes, int n_in,
                              void* d_out, int out_size, void* d_ws, size_t ws_size,
                              hipStream_t stream)
{
    const float* logits  = (const float*)d_in[0];
    const int*   targets = (const int*)d_in[1];
    float*       out     = (float*)d_out;

    float*        blk_sum = (float*)d_ws;
    unsigned int* blk_cnt = (unsigned int*)((char*)d_ws + GRID_ * sizeof(float));
    unsigned int* arrive  = (unsigned int*)((char*)d_ws + 2ull * GRID_ * sizeof(float));

    // Counter must be 0 at every launch (ws poisoned 0xAA once, never restored).
    hipMemsetAsync(arrive, 0, sizeof(unsigned int), stream);

    ohem_ce_fused<<<GRID_, BLOCK_, 0, stream>>>(logits, targets, blk_sum, blk_cnt,
                                                arrive, out);
}

// Round 5
// 58.027 us; speedup vs baseline: 4.5572x; 4.5572x over previous
//
#include <hip/hip_runtime.h>

// OHEM cross-entropy: per-pixel CE over C=19 channels, mean of losses > 0.7.
// logits [8,19,512,1024] f32 (N(0,1) -> no-max logsumexp is safe),
// targets [8,512,1024] i32.
//
// R5: revert to R3's proven two-kernel structure (58.1 us, ~95% of the
// 6.29 TB/s copy ceiling on the main kernel).
// R4 post-mortem (do NOT re-fuse): folding the final reduction into the main
// kernel (early-return CFG + fence/atomic tail) collapsed the register
// allocation of the hot loop to VGPR_Count=24 -> ~1-2 outstanding loads ->
// 640 GB/s latency-bound -> 264 us (4.5x regression). The unrolled 19-channel
// load schedule needs its own kernel with launch_bounds(256,8) to compile to
// ~64 VGPRs with ~10+ loads in flight.

typedef float f32x4 __attribute__((ext_vector_type(4)));
typedef int   i32x4 __attribute__((ext_vector_type(4)));

constexpr int       C_      = 19;
constexpr int       HW_     = 512 * 1024;          // 2^19
constexpr long long CHW_    = (long long)C_ * HW_;
constexpr int       NPIX_   = 8 * HW_;             // 4194304
constexpr int       NVEC_   = NPIX_ / 4;           // 1048576
constexpr float     THRESH_ = 0.7f;
constexpr int       IGNORE_ = 255;
constexpr int       BLOCK_  = 256;
constexpr int       GRID_   = NVEC_ / BLOCK_;      // 4096 blocks

__global__ __launch_bounds__(BLOCK_, 8) void ohem_ce_kernel(
    const float* __restrict__ logits,
    const int*   __restrict__ targets,
    float*        __restrict__ blk_sum,
    unsigned int* __restrict__ blk_cnt)
{
    const int tid = blockIdx.x * BLOCK_ + threadIdx.x;   // grid exactly covers NVEC_
    const int p0  = tid << 2;
    const int b   = p0 >> 19;                            // / HW_
    const int rem = p0 & (HW_ - 1);
    const float* base = logits + (long long)b * CHW_ + rem;

    const i32x4 tg = __builtin_nontemporal_load(
        reinterpret_cast<const i32x4*>(targets + p0));

    int ct[4];
    #pragma unroll
    for (int j = 0; j < 4; ++j) ct[j] = min(max(tg[j], 0), C_ - 1);

    float s[4]  = {0.f, 0.f, 0.f, 0.f};
    float xt[4] = {0.f, 0.f, 0.f, 0.f};

    #pragma unroll
    for (int c = 0; c < C_; ++c) {
        const f32x4 v = __builtin_nontemporal_load(
            reinterpret_cast<const f32x4*>(base + (long long)c * HW_));
        #pragma unroll
        for (int j = 0; j < 4; ++j) {
            s[j] += __expf(v[j]);
            if (c == ct[j]) xt[j] = v[j];   // select, never runtime-index regs
        }
    }

    float        lsum = 0.0f;
    unsigned int lcnt = 0u;
    #pragma unroll
    for (int j = 0; j < 4; ++j) {
        const float loss = __logf(s[j]) - xt[j];         // logsumexp (no max) - x_t
        if (tg[j] != IGNORE_ && loss > THRESH_) { lsum += loss; lcnt += 1u; }
    }

    // 64-lane wave reduction
    #pragma unroll
    for (int off = 32; off > 0; off >>= 1) {
        lsum += __shfl_down(lsum, off);
        lcnt += __shfl_down(lcnt, off);
    }

    __shared__ float        s_sum[4];
    __shared__ unsigned int s_cnt[4];
    const int lane = threadIdx.x & 63;
    const int wid  = threadIdx.x >> 6;
    if (lane == 0) { s_sum[wid] = lsum; s_cnt[wid] = lcnt; }
    __syncthreads();

    if (threadIdx.x == 0) {
        blk_sum[blockIdx.x] = s_sum[0] + s_sum[1] + s_sum[2] + s_sum[3];
        blk_cnt[blockIdx.x] = s_cnt[0] + s_cnt[1] + s_cnt[2] + s_cnt[3];
    }
}

// 1024 threads; thread t owns partials [4t, 4t+4) -> one f32x4 + one i32x4.
__global__ __launch_bounds__(1024) void ohem_finalize(
    const float*        __restrict__ blk_sum,
    const unsigned int* __restrict__ blk_cnt,
    float*              __restrict__ out)
{
    const int t = threadIdx.x;
    const f32x4 s4 = *reinterpret_cast<const f32x4*>(blk_sum + (t << 2));
    const i32x4 c4 = *reinterpret_cast<const i32x4*>(
        reinterpret_cast<const int*>(blk_cnt) + (t << 2));

    double       ds = (double)s4[0] + (double)s4[1] + (double)s4[2] + (double)s4[3];
    unsigned int dc = (unsigned int)c4[0] + (unsigned int)c4[1] +
                      (unsigned int)c4[2] + (unsigned int)c4[3];

    #pragma unroll
    for (int off = 32; off > 0; off >>= 1) {
        ds += __shfl_down(ds, off);
        dc += __shfl_down(dc, off);
    }

    __shared__ double       sd[16];
    __shared__ unsigned int sc[16];
    const int lane = t & 63;
    const int wid  = t >> 6;
    if (lane == 0) { sd[wid] = ds; sc[wid] = dc; }
    __syncthreads();

    if (t == 0) {
        double       tot = 0.0;
        unsigned int cnt = 0u;
        #pragma unroll
        for (int i = 0; i < 16; ++i) { tot += sd[i]; cnt += sc[i]; }
        out[0] = (float)(tot / (double)(cnt ? cnt : 1u));
    }
}

extern "C" void kernel_launch(void* const* d_in, const int* in_sizes, int n_in,
                              void* d_out, int out_size, void* d_ws, size_t ws_size,
                              hipStream_t stream)
{
    const float* logits  = (const float*)d_in[0];
    const int*   targets = (const int*)d_in[1];
    float*       out     = (float*)d_out;

    // Per-block partials in workspace: every block writes its slot every
    // launch -> no zeroing needed, no atomics, deterministic.
    float*        blk_sum = (float*)d_ws;
    unsigned int* blk_cnt = (unsigned int*)((char*)d_ws + GRID_ * sizeof(float));

    ohem_ce_kernel<<<GRID_, BLOCK_, 0, stream>>>(logits, targets, blk_sum, blk_cnt);
    ohem_finalize<<<1, 1024, 0, stream>>>(blk_sum, blk_cnt, out);
}